// Round 5
// baseline (830.976 us; speedup 1.0000x reference)
//
#include <hip/hip_runtime.h>
#include <hip/hip_bf16.h>

// GCN 3-layer forward, fp32 baseline.
// Pipeline: CSR build (counts -> scan -> fill), then per layer:
//   GEMM (+ dinv row prescale epilogue) -> CSR aggregation (+ fused BN/ReLU or bias).

#define GN 50000
#define GE 800000

// ---------------- graph setup kernels ----------------

__global__ __launch_bounds__(256) void init_kernel(int* counts, int* cursor) {
    int i = blockIdx.x * 256 + threadIdx.x;
    if (i < GN) { counts[i] = 0; cursor[i] = 0; }
}

__global__ __launch_bounds__(256) void count_kernel(const int* __restrict__ dst, int* __restrict__ counts) {
    int e = blockIdx.x * 256 + threadIdx.x;
    if (e < GE) atomicAdd(&counts[dst[e]], 1);
}

__global__ __launch_bounds__(256) void dinv_kernel(const int* __restrict__ counts, float* __restrict__ dinv) {
    int i = blockIdx.x * 256 + threadIdx.x;
    if (i < GN) dinv[i] = rsqrtf((float)counts[i] + 1.0f);  // +1 self loop
}

// single-block scan over counts -> exclusive row_ptr, row_ptr[N] = E
__global__ __launch_bounds__(1024) void scan_kernel(const int* __restrict__ counts, int* __restrict__ row_ptr) {
    __shared__ int sums[1024];
    int tid = threadIdx.x;
    int chunk = (GN + 1023) / 1024;
    int start = tid * chunk;
    int end = min(start + chunk, GN);
    int s = 0;
    for (int i = start; i < end; i++) s += counts[i];
    sums[tid] = s;
    __syncthreads();
    for (int off = 1; off < 1024; off <<= 1) {
        int v = (tid >= off) ? sums[tid - off] : 0;
        __syncthreads();
        sums[tid] += v;
        __syncthreads();
    }
    int run = (tid == 0) ? 0 : sums[tid - 1];
    for (int i = start; i < end; i++) { row_ptr[i] = run; run += counts[i]; }
    if (tid == 1023) row_ptr[GN] = sums[1023];
}

__global__ __launch_bounds__(256) void fill_kernel(const int* __restrict__ src, const int* __restrict__ dst,
                                                   const int* __restrict__ row_ptr, int* __restrict__ cursor,
                                                   int* __restrict__ col) {
    int e = blockIdx.x * 256 + threadIdx.x;
    if (e < GE) {
        int d = dst[e];
        int pos = row_ptr[d] + atomicAdd(&cursor[d], 1);
        col[pos] = src[e];
    }
}

// fused BN affine params: a = g*rsqrt(v+eps), c = (b-m)*a + be
__global__ __launch_bounds__(256) void params_kernel(
    const float* b1, const float* g1, const float* be1, const float* m1, const float* v1,
    const float* b2, const float* g2, const float* be2, const float* m2, const float* v2,
    float* prm) {
    int t = threadIdx.x;  // 256 threads
    float s1 = g1[t] * rsqrtf(v1[t] + 1e-5f);
    prm[0 * 256 + t] = s1;
    prm[1 * 256 + t] = (b1[t] - m1[t]) * s1 + be1[t];
    float s2 = g2[t] * rsqrtf(v2[t] + 1e-5f);
    prm[2 * 256 + t] = s2;
    prm[3 * 256 + t] = (b2[t] - m2[t]) * s2 + be2[t];
}

// ---------------- GEMM: C[m][n] = dinv[m] * sum_k A[m][k]*W[k][n] ----------------
// A: [M][256] row-major, W: [256][DO] row-major. Tile 64x64, BK=32, 256 thr, 4x4/thread.

template <int DO>
__global__ __launch_bounds__(256) void gemm_prescale(const float* __restrict__ A, const float* __restrict__ W,
                                                     const float* __restrict__ dinv, float* __restrict__ C, int M) {
    __shared__ float As[32][64 + 4];  // [k][m], padded
    __shared__ float Bs[32][64];      // [k][n]
    int tid = threadIdx.x;
    int m0 = blockIdx.x * 64;
    int n0 = blockIdx.y * 64;
    int tx = tid & 15, ty = tid >> 4;
    float acc[4][4] = {};

    int lr = tid >> 3;         // 0..31 (A row within half-tile)
    int lk = (tid & 7) * 4;    // 0..28 (A k-offset, float4)
    int bkr = tid >> 4;        // 0..15 (B k-row)
    int bn4 = (tid & 15) * 4;  // B n-offset, float4

    for (int k0 = 0; k0 < 256; k0 += 32) {
#pragma unroll
        for (int h = 0; h < 2; h++) {
            int row = lr + h * 32;
            float4 av = make_float4(0.f, 0.f, 0.f, 0.f);
            if (m0 + row < M) av = *(const float4*)&A[(size_t)(m0 + row) * 256 + k0 + lk];
            As[lk + 0][row] = av.x;
            As[lk + 1][row] = av.y;
            As[lk + 2][row] = av.z;
            As[lk + 3][row] = av.w;
        }
#pragma unroll
        for (int h = 0; h < 2; h++) {
            int kr = bkr + h * 16;
            *(float4*)&Bs[kr][bn4] = *(const float4*)&W[(size_t)(k0 + kr) * DO + n0 + bn4];
        }
        __syncthreads();
#pragma unroll
        for (int kk = 0; kk < 32; kk++) {
            float4 a4 = *(const float4*)&As[kk][ty * 4];
            float4 b4 = *(const float4*)&Bs[kk][tx * 4];
            float a[4] = {a4.x, a4.y, a4.z, a4.w};
            float b[4] = {b4.x, b4.y, b4.z, b4.w};
#pragma unroll
            for (int i = 0; i < 4; i++)
#pragma unroll
                for (int j = 0; j < 4; j++) acc[i][j] = fmaf(a[i], b[j], acc[i][j]);
        }
        __syncthreads();
    }
#pragma unroll
    for (int i = 0; i < 4; i++) {
        int m = m0 + ty * 4 + i;
        if (m < M) {
            float dv = dinv[m];
            float4 o = make_float4(acc[i][0] * dv, acc[i][1] * dv, acc[i][2] * dv, acc[i][3] * dv);
            *(float4*)&C[(size_t)m * DO + n0 + tx * 4] = o;
        }
    }
}

// ---------------- CSR aggregation ----------------
// out[i][:] = epilogue( dinv[i] * ( h'[i][:] + sum_{s in N(i)} h'[s][:] ) )
// MODE 1: val = relu(val*pa[d] + pc[d]); MODE 0: val = val + pa[d]
template <int D, int MODE>
__global__ __launch_bounds__(256) void agg_kernel(const float* __restrict__ Hs, const int* __restrict__ row_ptr,
                                                  const int* __restrict__ col, const float* __restrict__ dinv,
                                                  const float* __restrict__ pa, const float* __restrict__ pc,
                                                  float* __restrict__ out, int M) {
    constexpr int V = D / 64;  // floats per lane
    int w = blockIdx.x * 4 + (threadIdx.x >> 6);
    if (w >= M) return;
    int lane = threadIdx.x & 63;
    float acc[V];
    {
        const float* r = Hs + (size_t)w * D + lane * V;
        if constexpr (V == 4) {
            float4 v = *(const float4*)r;
            acc[0] = v.x; acc[1] = v.y; acc[2] = v.z; acc[3] = v.w;
        } else {
            float2 v = *(const float2*)r;
            acc[0] = v.x; acc[1] = v.y;
        }
    }
    int beg = row_ptr[w], end = row_ptr[w + 1];
    for (int e = beg; e < end; e++) {
        int s = col[e];
        const float* r = Hs + (size_t)s * D + lane * V;
        if constexpr (V == 4) {
            float4 v = *(const float4*)r;
            acc[0] += v.x; acc[1] += v.y; acc[2] += v.z; acc[3] += v.w;
        } else {
            float2 v = *(const float2*)r;
            acc[0] += v.x; acc[1] += v.y;
        }
    }
    float dv = dinv[w];
#pragma unroll
    for (int j = 0; j < V; j++) {
        int d = lane * V + j;
        float val = acc[j] * dv;
        if constexpr (MODE == 1)
            val = fmaxf(fmaf(val, pa[d], pc[d]), 0.f);
        else
            val += pa[d];
        out[(size_t)w * D + d] = val;
    }
}

// ---------------- launch ----------------

extern "C" void kernel_launch(void* const* d_in, const int* in_sizes, int n_in,
                              void* d_out, int out_size, void* d_ws, size_t ws_size,
                              hipStream_t stream) {
    const float* x = (const float*)d_in[0];
    const int* ei = (const int*)d_in[1];
    const int* srcIdx = ei;
    const int* dstIdx = ei + GE;
    const float* W1 = (const float*)d_in[2];
    const float* b1 = (const float*)d_in[3];
    const float* g1 = (const float*)d_in[4];
    const float* be1 = (const float*)d_in[5];
    const float* m1 = (const float*)d_in[6];
    const float* v1 = (const float*)d_in[7];
    const float* W2 = (const float*)d_in[8];
    const float* b2 = (const float*)d_in[9];
    const float* g2 = (const float*)d_in[10];
    const float* be2 = (const float*)d_in[11];
    const float* m2 = (const float*)d_in[12];
    const float* v2 = (const float*)d_in[13];
    const float* W3 = (const float*)d_in[14];
    const float* b3 = (const float*)d_in[15];
    float* out = (float*)d_out;

    size_t off = 0;
    char* wsb = (char*)d_ws;
    auto take = [&](size_t bytes) -> char* {
        char* p = wsb + off;
        off += (bytes + 255) & ~(size_t)255;
        return p;
    };
    float* dinv = (float*)take((size_t)GN * 4);
    int* counts = (int*)take((size_t)GN * 4);
    int* cursor = (int*)take((size_t)GN * 4);
    int* row_ptr = (int*)take((size_t)(GN + 1) * 4);
    int* col = (int*)take((size_t)GE * 4);
    float* prm = (float*)take(4 * 256 * 4);
    float* hA = (float*)take((size_t)GN * 256 * 4);
    float* hB = (float*)take((size_t)GN * 256 * 4);

    const float* a1 = prm + 0 * 256;
    const float* c1 = prm + 1 * 256;
    const float* a2 = prm + 2 * 256;
    const float* c2 = prm + 3 * 256;

    int nb = (GN + 255) / 256;
    int eb = (GE + 255) / 256;

    init_kernel<<<nb, 256, 0, stream>>>(counts, cursor);
    count_kernel<<<eb, 256, 0, stream>>>(dstIdx, counts);
    dinv_kernel<<<nb, 256, 0, stream>>>(counts, dinv);
    scan_kernel<<<1, 1024, 0, stream>>>(counts, row_ptr);
    fill_kernel<<<eb, 256, 0, stream>>>(srcIdx, dstIdx, row_ptr, cursor, col);
    params_kernel<<<1, 256, 0, stream>>>(b1, g1, be1, m1, v1, b2, g2, be2, m2, v2, prm);

    dim3 g1g((GN + 63) / 64, 4);
    dim3 g3g((GN + 63) / 64, 2);
    int ab = (GN + 3) / 4;

    // layer 1
    gemm_prescale<256><<<g1g, 256, 0, stream>>>(x, W1, dinv, hA, GN);
    agg_kernel<256, 1><<<ab, 256, 0, stream>>>(hA, row_ptr, col, dinv, a1, c1, hB, GN);
    // layer 2
    gemm_prescale<256><<<g1g, 256, 0, stream>>>(hB, W2, dinv, hA, GN);
    agg_kernel<256, 1><<<ab, 256, 0, stream>>>(hA, row_ptr, col, dinv, a2, c2, hB, GN);
    // layer 3
    gemm_prescale<128><<<g3g, 256, 0, stream>>>(hB, W3, dinv, hA, GN);
    agg_kernel<128, 0><<<ab, 256, 0, stream>>>(hA, row_ptr, col, dinv, b3, b3, out, GN);
}

// Round 8
// 684.535 us; speedup vs baseline: 1.2139x; 1.2139x over previous
//
#include <hip/hip_runtime.h>
#include <hip/hip_bf16.h>

// GCN 3-layer forward.
// CSR build -> per layer: split-bf16 MFMA GEMM (+dinv prescale) -> CSR agg (+BN/ReLU, writes bf16 hi/lo planes).
// Split-bf16: a = hi + lo (each bf16), A*B ~ hi*hi + hi*lo + lo*hi (rel err ~2^-18).

#define GN 50000
#define GE 800000

typedef float f32x4 __attribute__((ext_vector_type(4)));
typedef short bf16x8 __attribute__((ext_vector_type(8)));

static __device__ __forceinline__ ushort f2bf_rn(float f) {
    unsigned u = __float_as_uint(f);
    u += 0x7fffu + ((u >> 16) & 1u);
    return (ushort)(u >> 16);
}
static __device__ __forceinline__ float bf2f(ushort h) {
    return __uint_as_float(((unsigned)h) << 16);
}

// ---------------- graph setup ----------------

__global__ __launch_bounds__(256) void init_kernel(int* counts, int* cursor) {
    int i = blockIdx.x * 256 + threadIdx.x;
    if (i < GN) { counts[i] = 0; cursor[i] = 0; }
}

__global__ __launch_bounds__(256) void count_kernel(const int* __restrict__ dst, int* __restrict__ counts) {
    int e = blockIdx.x * 256 + threadIdx.x;
    if (e < GE) atomicAdd(&counts[dst[e]], 1);
}

__global__ __launch_bounds__(256) void dinv_kernel(const int* __restrict__ counts, float* __restrict__ dinv) {
    int i = blockIdx.x * 256 + threadIdx.x;
    if (i < GN) dinv[i] = rsqrtf((float)counts[i] + 1.0f);
}

__global__ __launch_bounds__(1024) void scan_kernel(const int* __restrict__ counts, int* __restrict__ row_ptr) {
    __shared__ int sums[1024];
    int tid = threadIdx.x;
    int chunk = (GN + 1023) / 1024;
    int start = tid * chunk;
    int end = min(start + chunk, GN);
    int s = 0;
    for (int i = start; i < end; i++) s += counts[i];
    sums[tid] = s;
    __syncthreads();
    for (int off = 1; off < 1024; off <<= 1) {
        int v = (tid >= off) ? sums[tid - off] : 0;
        __syncthreads();
        sums[tid] += v;
        __syncthreads();
    }
    int run = (tid == 0) ? 0 : sums[tid - 1];
    for (int i = start; i < end; i++) { row_ptr[i] = run; run += counts[i]; }
    if (tid == 1023) row_ptr[GN] = sums[1023];
}

__global__ __launch_bounds__(256) void fill_kernel(const int* __restrict__ src, const int* __restrict__ dst,
                                                   const int* __restrict__ row_ptr, int* __restrict__ cursor,
                                                   int* __restrict__ col) {
    int e = blockIdx.x * 256 + threadIdx.x;
    if (e < GE) {
        int d = dst[e];
        int pos = row_ptr[d] + atomicAdd(&cursor[d], 1);
        col[pos] = src[e];
    }
}

__global__ __launch_bounds__(256) void params_kernel(
    const float* b1, const float* g1, const float* be1, const float* m1, const float* v1,
    const float* b2, const float* g2, const float* be2, const float* m2, const float* v2,
    float* prm) {
    int t = threadIdx.x;
    float s1 = g1[t] * rsqrtf(v1[t] + 1e-5f);
    prm[0 * 256 + t] = s1;
    prm[1 * 256 + t] = (b1[t] - m1[t]) * s1 + be1[t];
    float s2 = g2[t] * rsqrtf(v2[t] + 1e-5f);
    prm[2 * 256 + t] = s2;
    prm[3 * 256 + t] = (b2[t] - m2[t]) * s2 + be2[t];
}

// ---------------- fp32 -> bf16 hi/lo split pre-passes ----------------

__global__ __launch_bounds__(256) void conv_split(const float* __restrict__ in, ushort* __restrict__ hi,
                                                  ushort* __restrict__ lo, int n4) {
    int i = blockIdx.x * 256 + threadIdx.x;
    if (i >= n4) return;
    float4 v = *(const float4*)&in[(size_t)i * 4];
    ushort4 h, l;
    h.x = f2bf_rn(v.x); l.x = f2bf_rn(v.x - bf2f(h.x));
    h.y = f2bf_rn(v.y); l.y = f2bf_rn(v.y - bf2f(h.y));
    h.z = f2bf_rn(v.z); l.z = f2bf_rn(v.z - bf2f(h.z));
    h.w = f2bf_rn(v.w); l.w = f2bf_rn(v.w - bf2f(h.w));
    *(ushort4*)&hi[(size_t)i * 4] = h;
    *(ushort4*)&lo[(size_t)i * 4] = l;
}

// W: [256][DO] fp32 -> WT hi/lo: [DO][256] bf16
__global__ __launch_bounds__(256) void transpose_w(const float* __restrict__ W, ushort* __restrict__ hiT,
                                                   ushort* __restrict__ loT, int DO) {
    int idx = blockIdx.x * 256 + threadIdx.x;
    if (idx >= DO * 256) return;
    int n = idx >> 8, k = idx & 255;
    float v = W[k * DO + n];
    ushort h = f2bf_rn(v);
    hiT[idx] = h;
    loT[idx] = f2bf_rn(v - bf2f(h));
}

// ---------------- split-bf16 MFMA GEMM ----------------
// C[m][n] = dinv[m] * sum_k A[m][k]*W[k][n];  A given as hi/lo planes [M][256],
// W given as transposed hi/lo planes [DO][256]. Tile BM=128,BN=128,BK=32; 4 waves (2x2), 64x64/wave.

template <int DO>
__global__ __launch_bounds__(256) void gemm_mfma(const ushort* __restrict__ Ahi, const ushort* __restrict__ Alo,
                                                 const ushort* __restrict__ Bhi, const ushort* __restrict__ Blo,
                                                 const float* __restrict__ dinv, float* __restrict__ C, int M) {
    __shared__ ushort lds[4][128][40];  // 80B rows (pad 16B) -> <=2-way bank conflict on ds_read_b128
    int tid = threadIdx.x;
    int lane = tid & 63;
    int wave = tid >> 6;
    int wm = wave >> 1, wn = wave & 1;
    int m0 = blockIdx.x * 128;
    int n0 = blockIdx.y * 128;
    int rsel = lane & 15;
    int ksel = (lane >> 4) * 8;

    f32x4 acc[4][4] = {};

    for (int k0 = 0; k0 < 256; k0 += 32) {
        auto stage = [&](const ushort* __restrict__ src, int baseRow, int rClamp, int p) {
#pragma unroll
            for (int j = 0; j < 2; j++) {
                int o = (tid + j * 256) * 16;  // byte offset in 8KB plane tile
                int row = o >> 6;              // 0..127
                int kb = o & 63;               // byte within 64B k-chunk
                int rg = min(baseRow + row, rClamp);
                uint4 v = *(const uint4*)((const char*)src + (size_t)rg * 512 + (size_t)k0 * 2 + kb);
                *(uint4*)((char*)&lds[p][row][0] + kb) = v;
            }
        };
        stage(Ahi, m0, M - 1, 0);
        stage(Alo, m0, M - 1, 1);
        stage(Bhi, n0, DO - 1, 2);
        stage(Blo, n0, DO - 1, 3);
        __syncthreads();

        bf16x8 bh[4], bl[4];
#pragma unroll
        for (int ni = 0; ni < 4; ni++) {
            bh[ni] = *(const bf16x8*)&lds[2][wn * 64 + ni * 16 + rsel][ksel];
            bl[ni] = *(const bf16x8*)&lds[3][wn * 64 + ni * 16 + rsel][ksel];
        }
#pragma unroll
        for (int mi = 0; mi < 4; mi++) {
            bf16x8 ah = *(const bf16x8*)&lds[0][wm * 64 + mi * 16 + rsel][ksel];
            bf16x8 al = *(const bf16x8*)&lds[1][wm * 64 + mi * 16 + rsel][ksel];
#pragma unroll
            for (int ni = 0; ni < 4; ni++) {
                acc[mi][ni] = __builtin_amdgcn_mfma_f32_16x16x32_bf16(ah, bh[ni], acc[mi][ni], 0, 0, 0);
                acc[mi][ni] = __builtin_amdgcn_mfma_f32_16x16x32_bf16(ah, bl[ni], acc[mi][ni], 0, 0, 0);
                acc[mi][ni] = __builtin_amdgcn_mfma_f32_16x16x32_bf16(al, bh[ni], acc[mi][ni], 0, 0, 0);
            }
        }
        __syncthreads();
    }

    // epilogue: C/D layout col=lane&15, row=(lane>>4)*4+j  [m89-verified]
#pragma unroll
    for (int mi = 0; mi < 4; mi++) {
#pragma unroll
        for (int j = 0; j < 4; j++) {
            int r = m0 + wm * 64 + mi * 16 + (lane >> 4) * 4 + j;
            if (r < M) {
                float dv = dinv[r];
#pragma unroll
                for (int ni = 0; ni < 4; ni++) {
                    int c = n0 + wn * 64 + ni * 16 + rsel;
                    C[(size_t)r * DO + c] = acc[mi][ni][j] * dv;
                }
            }
        }
    }
}

// ---------------- CSR aggregation (4-way unrolled gather) ----------------
// MODE 1: val = relu(val*pa+pc), write bf16 hi/lo planes. MODE 0: val += pa, write fp32.
template <int D, int MODE>
__global__ __launch_bounds__(256) void agg_kernel(const float* __restrict__ Hs, const int* __restrict__ row_ptr,
                                                  const int* __restrict__ col, const float* __restrict__ dinv,
                                                  const float* __restrict__ pa, const float* __restrict__ pc,
                                                  float* __restrict__ outF, ushort* __restrict__ outHi,
                                                  ushort* __restrict__ outLo, int M) {
    constexpr int V = D / 64;
    int w = blockIdx.x * 4 + (threadIdx.x >> 6);
    if (w >= M) return;
    int lane = threadIdx.x & 63;
    const float* base = Hs + lane * V;
    float acc[V];
    if constexpr (V == 4) {
        float4 v = *(const float4*)(base + (size_t)w * D);
        acc[0] = v.x; acc[1] = v.y; acc[2] = v.z; acc[3] = v.w;
    } else {
        float2 v = *(const float2*)(base + (size_t)w * D);
        acc[0] = v.x; acc[1] = v.y;
    }
    int e = row_ptr[w], end = row_ptr[w + 1];
    // 4 independent gathers in flight
    for (; e + 4 <= end; e += 4) {
        int s0 = col[e + 0], s1 = col[e + 1], s2 = col[e + 2], s3 = col[e + 3];
        if constexpr (V == 4) {
            float4 r0 = *(const float4*)(base + (size_t)s0 * D);
            float4 r1 = *(const float4*)(base + (size_t)s1 * D);
            float4 r2 = *(const float4*)(base + (size_t)s2 * D);
            float4 r3 = *(const float4*)(base + (size_t)s3 * D);
            acc[0] += r0.x + r1.x + r2.x + r3.x;
            acc[1] += r0.y + r1.y + r2.y + r3.y;
            acc[2] += r0.z + r1.z + r2.z + r3.z;
            acc[3] += r0.w + r1.w + r2.w + r3.w;
        } else {
            float2 r0 = *(const float2*)(base + (size_t)s0 * D);
            float2 r1 = *(const float2*)(base + (size_t)s1 * D);
            float2 r2 = *(const float2*)(base + (size_t)s2 * D);
            float2 r3 = *(const float2*)(base + (size_t)s3 * D);
            acc[0] += r0.x + r1.x + r2.x + r3.x;
            acc[1] += r0.y + r1.y + r2.y + r3.y;
        }
    }
    for (; e < end; e++) {
        int s = col[e];
        if constexpr (V == 4) {
            float4 v = *(const float4*)(base + (size_t)s * D);
            acc[0] += v.x; acc[1] += v.y; acc[2] += v.z; acc[3] += v.w;
        } else {
            float2 v = *(const float2*)(base + (size_t)s * D);
            acc[0] += v.x; acc[1] += v.y;
        }
    }
    float dv = dinv[w];
    if constexpr (MODE == 1) {
        ushort4 h, l;
        float val;
        int d = lane * V;
        val = fmaxf(fmaf(acc[0] * dv, pa[d + 0], pc[d + 0]), 0.f);
        h.x = f2bf_rn(val); l.x = f2bf_rn(val - bf2f(h.x));
        val = fmaxf(fmaf(acc[1] * dv, pa[d + 1], pc[d + 1]), 0.f);
        h.y = f2bf_rn(val); l.y = f2bf_rn(val - bf2f(h.y));
        val = fmaxf(fmaf(acc[2] * dv, pa[d + 2], pc[d + 2]), 0.f);
        h.z = f2bf_rn(val); l.z = f2bf_rn(val - bf2f(h.z));
        val = fmaxf(fmaf(acc[3] * dv, pa[d + 3], pc[d + 3]), 0.f);
        h.w = f2bf_rn(val); l.w = f2bf_rn(val - bf2f(h.w));
        *(ushort4*)&outHi[(size_t)w * D + d] = h;
        *(ushort4*)&outLo[(size_t)w * D + d] = l;
    } else {
#pragma unroll
        for (int j = 0; j < V; j++) {
            int d = lane * V + j;
            outF[(size_t)w * D + d] = acc[j] * dv + pa[d];
        }
    }
}

// ---------------- launch ----------------

extern "C" void kernel_launch(void* const* d_in, const int* in_sizes, int n_in,
                              void* d_out, int out_size, void* d_ws, size_t ws_size,
                              hipStream_t stream) {
    const float* x = (const float*)d_in[0];
    const int* ei = (const int*)d_in[1];
    const int* srcIdx = ei;
    const int* dstIdx = ei + GE;
    const float* W1 = (const float*)d_in[2];
    const float* b1 = (const float*)d_in[3];
    const float* g1 = (const float*)d_in[4];
    const float* be1 = (const float*)d_in[5];
    const float* m1 = (const float*)d_in[6];
    const float* v1 = (const float*)d_in[7];
    const float* W2 = (const float*)d_in[8];
    const float* b2 = (const float*)d_in[9];
    const float* g2 = (const float*)d_in[10];
    const float* be2 = (const float*)d_in[11];
    const float* m2 = (const float*)d_in[12];
    const float* v2 = (const float*)d_in[13];
    const float* W3 = (const float*)d_in[14];
    const float* b3 = (const float*)d_in[15];
    float* out = (float*)d_out;

    size_t off = 0;
    char* wsb = (char*)d_ws;
    auto take = [&](size_t bytes) -> char* {
        char* p = wsb + off;
        off += (bytes + 255) & ~(size_t)255;
        return p;
    };
    float* dinv = (float*)take((size_t)GN * 4);
    int* counts = (int*)take((size_t)GN * 4);
    int* cursor = (int*)take((size_t)GN * 4);
    int* row_ptr = (int*)take((size_t)(GN + 1) * 4);
    int* col = (int*)take((size_t)GE * 4);
    float* prm = (float*)take(4 * 256 * 4);
    float* hA = (float*)take((size_t)GN * 256 * 4);     // GEMM output (fp32), reused all layers
    ushort* Phi = (ushort*)take((size_t)GN * 256 * 2);  // activation hi plane (x-planes aliased here)
    ushort* Plo = (ushort*)take((size_t)GN * 256 * 2);  // activation lo plane
    ushort* WT1h = (ushort*)take(256 * 256 * 2);
    ushort* WT1l = (ushort*)take(256 * 256 * 2);
    ushort* WT2h = (ushort*)take(256 * 256 * 2);
    ushort* WT2l = (ushort*)take(256 * 256 * 2);
    ushort* WT3h = (ushort*)take(128 * 256 * 2);
    ushort* WT3l = (ushort*)take(128 * 256 * 2);

    const float* a1 = prm + 0 * 256;
    const float* c1 = prm + 1 * 256;
    const float* a2 = prm + 2 * 256;
    const float* c2 = prm + 3 * 256;

    int nb = (GN + 255) / 256;
    int eb = (GE + 255) / 256;

    init_kernel<<<nb, 256, 0, stream>>>(counts, cursor);
    count_kernel<<<eb, 256, 0, stream>>>(dstIdx, counts);
    dinv_kernel<<<nb, 256, 0, stream>>>(counts, dinv);
    scan_kernel<<<1, 1024, 0, stream>>>(counts, row_ptr);
    fill_kernel<<<eb, 256, 0, stream>>>(srcIdx, dstIdx, row_ptr, cursor, col);
    params_kernel<<<1, 256, 0, stream>>>(b1, g1, be1, m1, v1, b2, g2, be2, m2, v2, prm);

    // pre-passes: split x and W transposes into bf16 hi/lo
    int n4 = GN * 64;  // GN*256/4 float4s
    conv_split<<<(n4 + 255) / 256, 256, 0, stream>>>(x, Phi, Plo, n4);
    transpose_w<<<(256 * 256 + 255) / 256, 256, 0, stream>>>(W1, WT1h, WT1l, 256);
    transpose_w<<<(256 * 256 + 255) / 256, 256, 0, stream>>>(W2, WT2h, WT2l, 256);
    transpose_w<<<(128 * 256 + 255) / 256, 256, 0, stream>>>(W3, WT3h, WT3l, 128);

    dim3 gg((GN + 127) / 128, 2);
    dim3 gg3((GN + 127) / 128, 1);
    int ab = (GN + 3) / 4;

    // layer 1
    gemm_mfma<256><<<gg, 256, 0, stream>>>(Phi, Plo, WT1h, WT1l, dinv, hA, GN);
    agg_kernel<256, 1><<<ab, 256, 0, stream>>>(hA, row_ptr, col, dinv, a1, c1, nullptr, Phi, Plo, GN);
    // layer 2
    gemm_mfma<256><<<gg, 256, 0, stream>>>(Phi, Plo, WT2h, WT2l, dinv, hA, GN);
    agg_kernel<256, 1><<<ab, 256, 0, stream>>>(hA, row_ptr, col, dinv, a2, c2, nullptr, Phi, Plo, GN);
    // layer 3
    gemm_mfma<128><<<gg3, 256, 0, stream>>>(Phi, Plo, WT3h, WT3l, dinv, hA, GN);
    agg_kernel<128, 0><<<ab, 256, 0, stream>>>(hA, row_ptr, col, dinv, b3, b3, out, nullptr, nullptr, GN);
}

// Round 9
// 549.795 us; speedup vs baseline: 1.5114x; 1.2451x over previous
//
#include <hip/hip_runtime.h>
#include <hip/hip_bf16.h>
#include <hip/hip_fp16.h>

// GCN 3-layer forward.
// CSR build -> per layer: split-bf16 MFMA GEMM (+dinv prescale, fp16 output) ->
//   CSR agg over fp16 rows (+BN/ReLU, writes bf16 hi/lo planes for next GEMM).
// Split-bf16: a = hi + lo (each bf16), A*B ~ hi*hi + hi*lo + lo*hi (rel err ~2^-18).
// GEMM->agg hop is fp16 (rel err 2.4e-4): halves the random-gather HBM traffic,
// which round-8 counters showed is BW-bound (398MB @ 3.75TB/s per agg dispatch).

#define GN 50000
#define GE 800000

typedef float f32x4 __attribute__((ext_vector_type(4)));
typedef short bf16x8 __attribute__((ext_vector_type(8)));

static __device__ __forceinline__ ushort f2bf_rn(float f) {
    unsigned u = __float_as_uint(f);
    u += 0x7fffu + ((u >> 16) & 1u);
    return (ushort)(u >> 16);
}
static __device__ __forceinline__ float bf2f(ushort h) {
    return __uint_as_float(((unsigned)h) << 16);
}

// ---------------- graph setup ----------------

__global__ __launch_bounds__(256) void init_kernel(int* counts, int* cursor) {
    int i = blockIdx.x * 256 + threadIdx.x;
    if (i < GN) { counts[i] = 0; cursor[i] = 0; }
}

__global__ __launch_bounds__(256) void count_kernel(const int* __restrict__ dst, int* __restrict__ counts) {
    int e = blockIdx.x * 256 + threadIdx.x;
    if (e < GE) atomicAdd(&counts[dst[e]], 1);
}

__global__ __launch_bounds__(256) void dinv_kernel(const int* __restrict__ counts, float* __restrict__ dinv) {
    int i = blockIdx.x * 256 + threadIdx.x;
    if (i < GN) dinv[i] = rsqrtf((float)counts[i] + 1.0f);
}

__global__ __launch_bounds__(1024) void scan_kernel(const int* __restrict__ counts, int* __restrict__ row_ptr) {
    __shared__ int sums[1024];
    int tid = threadIdx.x;
    int chunk = (GN + 1023) / 1024;
    int start = tid * chunk;
    int end = min(start + chunk, GN);
    int s = 0;
    for (int i = start; i < end; i++) s += counts[i];
    sums[tid] = s;
    __syncthreads();
    for (int off = 1; off < 1024; off <<= 1) {
        int v = (tid >= off) ? sums[tid - off] : 0;
        __syncthreads();
        sums[tid] += v;
        __syncthreads();
    }
    int run = (tid == 0) ? 0 : sums[tid - 1];
    for (int i = start; i < end; i++) { row_ptr[i] = run; run += counts[i]; }
    if (tid == 1023) row_ptr[GN] = sums[1023];
}

__global__ __launch_bounds__(256) void fill_kernel(const int* __restrict__ src, const int* __restrict__ dst,
                                                   const int* __restrict__ row_ptr, int* __restrict__ cursor,
                                                   int* __restrict__ col) {
    int e = blockIdx.x * 256 + threadIdx.x;
    if (e < GE) {
        int d = dst[e];
        int pos = row_ptr[d] + atomicAdd(&cursor[d], 1);
        col[pos] = src[e];
    }
}

__global__ __launch_bounds__(256) void params_kernel(
    const float* b1, const float* g1, const float* be1, const float* m1, const float* v1,
    const float* b2, const float* g2, const float* be2, const float* m2, const float* v2,
    float* prm) {
    int t = threadIdx.x;
    float s1 = g1[t] * rsqrtf(v1[t] + 1e-5f);
    prm[0 * 256 + t] = s1;
    prm[1 * 256 + t] = (b1[t] - m1[t]) * s1 + be1[t];
    float s2 = g2[t] * rsqrtf(v2[t] + 1e-5f);
    prm[2 * 256 + t] = s2;
    prm[3 * 256 + t] = (b2[t] - m2[t]) * s2 + be2[t];
}

// ---------------- fp32 -> bf16 hi/lo split pre-passes ----------------

__global__ __launch_bounds__(256) void conv_split(const float* __restrict__ in, ushort* __restrict__ hi,
                                                  ushort* __restrict__ lo, int n4) {
    int i = blockIdx.x * 256 + threadIdx.x;
    if (i >= n4) return;
    float4 v = *(const float4*)&in[(size_t)i * 4];
    ushort4 h, l;
    h.x = f2bf_rn(v.x); l.x = f2bf_rn(v.x - bf2f(h.x));
    h.y = f2bf_rn(v.y); l.y = f2bf_rn(v.y - bf2f(h.y));
    h.z = f2bf_rn(v.z); l.z = f2bf_rn(v.z - bf2f(h.z));
    h.w = f2bf_rn(v.w); l.w = f2bf_rn(v.w - bf2f(h.w));
    *(ushort4*)&hi[(size_t)i * 4] = h;
    *(ushort4*)&lo[(size_t)i * 4] = l;
}

// W: [256][DO] fp32 -> WT hi/lo: [DO][256] bf16
__global__ __launch_bounds__(256) void transpose_w(const float* __restrict__ W, ushort* __restrict__ hiT,
                                                   ushort* __restrict__ loT, int DO) {
    int idx = blockIdx.x * 256 + threadIdx.x;
    if (idx >= DO * 256) return;
    int n = idx >> 8, k = idx & 255;
    float v = W[k * DO + n];
    ushort h = f2bf_rn(v);
    hiT[idx] = h;
    loT[idx] = f2bf_rn(v - bf2f(h));
}

// ---------------- split-bf16 MFMA GEMM (fp16 output) ----------------
// C[m][n] = dinv[m] * sum_k A[m][k]*W[k][n];  A hi/lo planes [M][256],
// W transposed hi/lo planes [DO][256]. Tile BM=128,BN=128,BK=32; 4 waves (2x2), 64x64/wave.

template <int DO>
__global__ __launch_bounds__(256) void gemm_mfma(const ushort* __restrict__ Ahi, const ushort* __restrict__ Alo,
                                                 const ushort* __restrict__ Bhi, const ushort* __restrict__ Blo,
                                                 const float* __restrict__ dinv, __half* __restrict__ C, int M) {
    __shared__ ushort lds[4][128][40];  // 80B rows (pad 16B) -> <=2-way bank conflict on ds_read_b128
    int tid = threadIdx.x;
    int lane = tid & 63;
    int wave = tid >> 6;
    int wm = wave >> 1, wn = wave & 1;
    int m0 = blockIdx.x * 128;
    int n0 = blockIdx.y * 128;
    int rsel = lane & 15;
    int ksel = (lane >> 4) * 8;

    f32x4 acc[4][4] = {};

    for (int k0 = 0; k0 < 256; k0 += 32) {
        auto stage = [&](const ushort* __restrict__ src, int baseRow, int rClamp, int p) {
#pragma unroll
            for (int j = 0; j < 2; j++) {
                int o = (tid + j * 256) * 16;  // byte offset in 8KB plane tile
                int row = o >> 6;              // 0..127
                int kb = o & 63;               // byte within 64B k-chunk
                int rg = min(baseRow + row, rClamp);
                uint4 v = *(const uint4*)((const char*)src + (size_t)rg * 512 + (size_t)k0 * 2 + kb);
                *(uint4*)((char*)&lds[p][row][0] + kb) = v;
            }
        };
        stage(Ahi, m0, M - 1, 0);
        stage(Alo, m0, M - 1, 1);
        stage(Bhi, n0, DO - 1, 2);
        stage(Blo, n0, DO - 1, 3);
        __syncthreads();

        bf16x8 bh[4], bl[4];
#pragma unroll
        for (int ni = 0; ni < 4; ni++) {
            bh[ni] = *(const bf16x8*)&lds[2][wn * 64 + ni * 16 + rsel][ksel];
            bl[ni] = *(const bf16x8*)&lds[3][wn * 64 + ni * 16 + rsel][ksel];
        }
#pragma unroll
        for (int mi = 0; mi < 4; mi++) {
            bf16x8 ah = *(const bf16x8*)&lds[0][wm * 64 + mi * 16 + rsel][ksel];
            bf16x8 al = *(const bf16x8*)&lds[1][wm * 64 + mi * 16 + rsel][ksel];
#pragma unroll
            for (int ni = 0; ni < 4; ni++) {
                acc[mi][ni] = __builtin_amdgcn_mfma_f32_16x16x32_bf16(ah, bh[ni], acc[mi][ni], 0, 0, 0);
                acc[mi][ni] = __builtin_amdgcn_mfma_f32_16x16x32_bf16(ah, bl[ni], acc[mi][ni], 0, 0, 0);
                acc[mi][ni] = __builtin_amdgcn_mfma_f32_16x16x32_bf16(al, bh[ni], acc[mi][ni], 0, 0, 0);
            }
        }
        __syncthreads();
    }

    // epilogue: C/D layout col=lane&15, row=(lane>>4)*4+j  [m89-verified]; fp16 store
#pragma unroll
    for (int mi = 0; mi < 4; mi++) {
#pragma unroll
        for (int j = 0; j < 4; j++) {
            int r = m0 + wm * 64 + mi * 16 + (lane >> 4) * 4 + j;
            if (r < M) {
                float dv = dinv[r];
#pragma unroll
                for (int ni = 0; ni < 4; ni++) {
                    int c = n0 + wn * 64 + ni * 16 + rsel;
                    C[(size_t)r * DO + c] = __float2half_rn(acc[mi][ni][j] * dv);
                }
            }
        }
    }
}

// ---------------- CSR aggregation over fp16 rows (4-way unrolled gather) ----------------
// MODE 1: val = relu(val*pa+pc), write bf16 hi/lo planes. MODE 0: val = val + pa, write fp32.
template <int D, int MODE>
__global__ __launch_bounds__(256) void agg_kernel(const __half* __restrict__ Hs, const int* __restrict__ row_ptr,
                                                  const int* __restrict__ col, const float* __restrict__ dinv,
                                                  const float* __restrict__ pa, const float* __restrict__ pc,
                                                  float* __restrict__ outF, ushort* __restrict__ outHi,
                                                  ushort* __restrict__ outLo, int M) {
    constexpr int V = D / 64;  // halfs per lane: 4 (D=256) or 2 (D=128)
    int w = blockIdx.x * 4 + (threadIdx.x >> 6);
    if (w >= M) return;
    int lane = threadIdx.x & 63;
    const __half* base = Hs + lane * V;
    float acc[V];

    auto addrow = [&](const __half* p) {
        if constexpr (V == 4) {
            __half2 v01 = *(const __half2*)(p);
            __half2 v23 = *(const __half2*)(p + 2);
            float2 f0 = __half22float2(v01);
            float2 f1 = __half22float2(v23);
            acc[0] += f0.x; acc[1] += f0.y; acc[2] += f1.x; acc[3] += f1.y;
        } else {
            __half2 v01 = *(const __half2*)(p);
            float2 f0 = __half22float2(v01);
            acc[0] += f0.x; acc[1] += f0.y;
        }
    };
#pragma unroll
    for (int j = 0; j < V; j++) acc[j] = 0.f;
    addrow(base + (size_t)w * D);  // self loop

    int e = row_ptr[w], end = row_ptr[w + 1];
    for (; e + 4 <= end; e += 4) {
        int s0 = col[e + 0], s1 = col[e + 1], s2 = col[e + 2], s3 = col[e + 3];
        addrow(base + (size_t)s0 * D);
        addrow(base + (size_t)s1 * D);
        addrow(base + (size_t)s2 * D);
        addrow(base + (size_t)s3 * D);
    }
    for (; e < end; e++) addrow(base + (size_t)col[e] * D);

    float dv = dinv[w];
    if constexpr (MODE == 1) {
        ushort4 h, l;
        float val;
        int d = lane * V;
        val = fmaxf(fmaf(acc[0] * dv, pa[d + 0], pc[d + 0]), 0.f);
        h.x = f2bf_rn(val); l.x = f2bf_rn(val - bf2f(h.x));
        val = fmaxf(fmaf(acc[1] * dv, pa[d + 1], pc[d + 1]), 0.f);
        h.y = f2bf_rn(val); l.y = f2bf_rn(val - bf2f(h.y));
        val = fmaxf(fmaf(acc[2] * dv, pa[d + 2], pc[d + 2]), 0.f);
        h.z = f2bf_rn(val); l.z = f2bf_rn(val - bf2f(h.z));
        val = fmaxf(fmaf(acc[3] * dv, pa[d + 3], pc[d + 3]), 0.f);
        h.w = f2bf_rn(val); l.w = f2bf_rn(val - bf2f(h.w));
        *(ushort4*)&outHi[(size_t)w * D + d] = h;
        *(ushort4*)&outLo[(size_t)w * D + d] = l;
    } else {
#pragma unroll
        for (int j = 0; j < V; j++) {
            int d = lane * V + j;
            outF[(size_t)w * D + d] = acc[j] * dv + pa[d];
        }
    }
}

// ---------------- launch ----------------

extern "C" void kernel_launch(void* const* d_in, const int* in_sizes, int n_in,
                              void* d_out, int out_size, void* d_ws, size_t ws_size,
                              hipStream_t stream) {
    const float* x = (const float*)d_in[0];
    const int* ei = (const int*)d_in[1];
    const int* srcIdx = ei;
    const int* dstIdx = ei + GE;
    const float* W1 = (const float*)d_in[2];
    const float* b1 = (const float*)d_in[3];
    const float* g1 = (const float*)d_in[4];
    const float* be1 = (const float*)d_in[5];
    const float* m1 = (const float*)d_in[6];
    const float* v1 = (const float*)d_in[7];
    const float* W2 = (const float*)d_in[8];
    const float* b2 = (const float*)d_in[9];
    const float* g2 = (const float*)d_in[10];
    const float* be2 = (const float*)d_in[11];
    const float* m2 = (const float*)d_in[12];
    const float* v2 = (const float*)d_in[13];
    const float* W3 = (const float*)d_in[14];
    const float* b3 = (const float*)d_in[15];
    float* out = (float*)d_out;

    size_t off = 0;
    char* wsb = (char*)d_ws;
    auto take = [&](size_t bytes) -> char* {
        char* p = wsb + off;
        off += (bytes + 255) & ~(size_t)255;
        return p;
    };
    float* dinv = (float*)take((size_t)GN * 4);
    int* counts = (int*)take((size_t)GN * 4);
    int* cursor = (int*)take((size_t)GN * 4);
    int* row_ptr = (int*)take((size_t)(GN + 1) * 4);
    int* col = (int*)take((size_t)GE * 4);
    float* prm = (float*)take(4 * 256 * 4);
    __half* hH = (__half*)take((size_t)GN * 256 * 2);   // GEMM output (fp16), reused all layers
    ushort* Phi = (ushort*)take((size_t)GN * 256 * 2);  // activation hi plane (x-planes aliased here)
    ushort* Plo = (ushort*)take((size_t)GN * 256 * 2);  // activation lo plane
    ushort* WT1h = (ushort*)take(256 * 256 * 2);
    ushort* WT1l = (ushort*)take(256 * 256 * 2);
    ushort* WT2h = (ushort*)take(256 * 256 * 2);
    ushort* WT2l = (ushort*)take(256 * 256 * 2);
    ushort* WT3h = (ushort*)take(128 * 256 * 2);
    ushort* WT3l = (ushort*)take(128 * 256 * 2);

    const float* a1 = prm + 0 * 256;
    const float* c1 = prm + 1 * 256;
    const float* a2 = prm + 2 * 256;
    const float* c2 = prm + 3 * 256;

    int nb = (GN + 255) / 256;
    int eb = (GE + 255) / 256;

    init_kernel<<<nb, 256, 0, stream>>>(counts, cursor);
    count_kernel<<<eb, 256, 0, stream>>>(dstIdx, counts);
    dinv_kernel<<<nb, 256, 0, stream>>>(counts, dinv);
    scan_kernel<<<1, 1024, 0, stream>>>(counts, row_ptr);
    fill_kernel<<<eb, 256, 0, stream>>>(srcIdx, dstIdx, row_ptr, cursor, col);
    params_kernel<<<1, 256, 0, stream>>>(b1, g1, be1, m1, v1, b2, g2, be2, m2, v2, prm);

    // pre-passes: split x and W transposes into bf16 hi/lo
    int n4 = GN * 64;  // GN*256/4 float4s
    conv_split<<<(n4 + 255) / 256, 256, 0, stream>>>(x, Phi, Plo, n4);
    transpose_w<<<(256 * 256 + 255) / 256, 256, 0, stream>>>(W1, WT1h, WT1l, 256);
    transpose_w<<<(256 * 256 + 255) / 256, 256, 0, stream>>>(W2, WT2h, WT2l, 256);
    transpose_w<<<(128 * 256 + 255) / 256, 256, 0, stream>>>(W3, WT3h, WT3l, 128);

    dim3 gg((GN + 127) / 128, 2);
    dim3 gg3((GN + 127) / 128, 1);
    int ab = (GN + 3) / 4;

    // layer 1
    gemm_mfma<256><<<gg, 256, 0, stream>>>(Phi, Plo, WT1h, WT1l, dinv, hH, GN);
    agg_kernel<256, 1><<<ab, 256, 0, stream>>>(hH, row_ptr, col, dinv, a1, c1, nullptr, Phi, Plo, GN);
    // layer 2
    gemm_mfma<256><<<gg, 256, 0, stream>>>(Phi, Plo, WT2h, WT2l, dinv, hH, GN);
    agg_kernel<256, 1><<<ab, 256, 0, stream>>>(hH, row_ptr, col, dinv, a2, c2, nullptr, Phi, Plo, GN);
    // layer 3
    gemm_mfma<128><<<gg3, 256, 0, stream>>>(Phi, Plo, WT3h, WT3l, dinv, hH, GN);
    agg_kernel<128, 0><<<ab, 256, 0, stream>>>(hH, row_ptr, col, dinv, b3, b3, out, nullptr, nullptr, GN);
}

// Round 10
// 487.492 us; speedup vs baseline: 1.7046x; 1.1278x over previous
//
#include <hip/hip_runtime.h>
#include <hip/hip_bf16.h>
#include <hip/hip_fp16.h>

// GCN 3-layer forward.
// CSR build (count -> atomic segment alloc -> fill) -> per layer:
//   split-bf16 MFMA GEMM (+dinv prescale, fp16 output) ->
//   CSR agg over fp16 rows, 8-deep gather pipeline (+BN/ReLU, writes bf16 hi/lo planes).
// Split-bf16: a = hi + lo (each bf16), A*B ~ hi*hi + hi*lo + lo*hi (rel err ~2^-18).
// Round-9 lesson: single-block scan was 78us (top dispatch); segments need not be a
// prefix scan -- wave-aggregated atomicAdd allocation is ~3us and order-free.

#define GN 50000
#define GE 800000

typedef float f32x4 __attribute__((ext_vector_type(4)));
typedef short bf16x8 __attribute__((ext_vector_type(8)));

static __device__ __forceinline__ ushort f2bf_rn(float f) {
    unsigned u = __float_as_uint(f);
    u += 0x7fffu + ((u >> 16) & 1u);
    return (ushort)(u >> 16);
}
static __device__ __forceinline__ float bf2f(ushort h) {
    return __uint_as_float(((unsigned)h) << 16);
}

// ---------------- graph setup ----------------

__global__ __launch_bounds__(256) void init_kernel(int* counts, int* cursor, int* total) {
    int i = blockIdx.x * 256 + threadIdx.x;
    if (i < GN) { counts[i] = 0; cursor[i] = 0; }
    if (i == 0) *total = 0;
}

__global__ __launch_bounds__(256) void count_kernel(const int* __restrict__ dst, int* __restrict__ counts) {
    int e = blockIdx.x * 256 + threadIdx.x;
    if (e < GE) atomicAdd(&counts[dst[e]], 1);
}

__global__ __launch_bounds__(256) void dinv_kernel(const int* __restrict__ counts, float* __restrict__ dinv) {
    int i = blockIdx.x * 256 + threadIdx.x;
    if (i < GN) dinv[i] = rsqrtf((float)counts[i] + 1.0f);
}

// disjoint CSR segment allocation: base[i] = atomic segment start for node i.
// Wave-level: 64-lane shfl scan, one atomicAdd per wave.
__global__ __launch_bounds__(256) void alloc_kernel(const int* __restrict__ counts, int* __restrict__ base,
                                                    int* __restrict__ total) {
    int i = blockIdx.x * 256 + threadIdx.x;
    int lane = threadIdx.x & 63;
    int c = (i < GN) ? counts[i] : 0;
    int v = c;
#pragma unroll
    for (int off = 1; off < 64; off <<= 1) {
        int t = __shfl_up(v, off);
        if (lane >= off) v += t;
    }
    int waveSum = __shfl(v, 63);
    int wb = 0;
    if (lane == 63) wb = atomicAdd(total, waveSum);
    wb = __shfl(wb, 63);
    if (i < GN) base[i] = wb + v - c;  // exclusive intra-wave prefix + wave base
}

__global__ __launch_bounds__(256) void fill_kernel(const int* __restrict__ src, const int* __restrict__ dst,
                                                   const int* __restrict__ base, int* __restrict__ cursor,
                                                   int* __restrict__ col) {
    int e = blockIdx.x * 256 + threadIdx.x;
    if (e < GE) {
        int d = dst[e];
        int pos = base[d] + atomicAdd(&cursor[d], 1);
        col[pos] = src[e];
    }
}

__global__ __launch_bounds__(256) void params_kernel(
    const float* b1, const float* g1, const float* be1, const float* m1, const float* v1,
    const float* b2, const float* g2, const float* be2, const float* m2, const float* v2,
    float* prm) {
    int t = threadIdx.x;
    float s1 = g1[t] * rsqrtf(v1[t] + 1e-5f);
    prm[0 * 256 + t] = s1;
    prm[1 * 256 + t] = (b1[t] - m1[t]) * s1 + be1[t];
    float s2 = g2[t] * rsqrtf(v2[t] + 1e-5f);
    prm[2 * 256 + t] = s2;
    prm[3 * 256 + t] = (b2[t] - m2[t]) * s2 + be2[t];
}

// ---------------- fp32 -> bf16 hi/lo split pre-passes ----------------

__global__ __launch_bounds__(256) void conv_split(const float* __restrict__ in, ushort* __restrict__ hi,
                                                  ushort* __restrict__ lo, int n4) {
    int i = blockIdx.x * 256 + threadIdx.x;
    if (i >= n4) return;
    float4 v = *(const float4*)&in[(size_t)i * 4];
    ushort4 h, l;
    h.x = f2bf_rn(v.x); l.x = f2bf_rn(v.x - bf2f(h.x));
    h.y = f2bf_rn(v.y); l.y = f2bf_rn(v.y - bf2f(h.y));
    h.z = f2bf_rn(v.z); l.z = f2bf_rn(v.z - bf2f(h.z));
    h.w = f2bf_rn(v.w); l.w = f2bf_rn(v.w - bf2f(h.w));
    *(ushort4*)&hi[(size_t)i * 4] = h;
    *(ushort4*)&lo[(size_t)i * 4] = l;
}

// W: [256][DO] fp32 -> WT hi/lo: [DO][256] bf16
__global__ __launch_bounds__(256) void transpose_w(const float* __restrict__ W, ushort* __restrict__ hiT,
                                                   ushort* __restrict__ loT, int DO) {
    int idx = blockIdx.x * 256 + threadIdx.x;
    if (idx >= DO * 256) return;
    int n = idx >> 8, k = idx & 255;
    float v = W[k * DO + n];
    ushort h = f2bf_rn(v);
    hiT[idx] = h;
    loT[idx] = f2bf_rn(v - bf2f(h));
}

// ---------------- split-bf16 MFMA GEMM (fp16 output) ----------------
// C[m][n] = dinv[m] * sum_k A[m][k]*W[k][n];  A hi/lo planes [M][256],
// W transposed hi/lo planes [DO][256]. Tile BM=128,BN=128,BK=32; 4 waves (2x2), 64x64/wave.

template <int DO>
__global__ __launch_bounds__(256) void gemm_mfma(const ushort* __restrict__ Ahi, const ushort* __restrict__ Alo,
                                                 const ushort* __restrict__ Bhi, const ushort* __restrict__ Blo,
                                                 const float* __restrict__ dinv, __half* __restrict__ C, int M) {
    __shared__ ushort lds[4][128][40];  // 80B rows (pad 16B) -> <=2-way bank conflict on ds_read_b128
    int tid = threadIdx.x;
    int lane = tid & 63;
    int wave = tid >> 6;
    int wm = wave >> 1, wn = wave & 1;
    int m0 = blockIdx.x * 128;
    int n0 = blockIdx.y * 128;
    int rsel = lane & 15;
    int ksel = (lane >> 4) * 8;

    f32x4 acc[4][4] = {};

    for (int k0 = 0; k0 < 256; k0 += 32) {
        auto stage = [&](const ushort* __restrict__ src, int baseRow, int rClamp, int p) {
#pragma unroll
            for (int j = 0; j < 2; j++) {
                int o = (tid + j * 256) * 16;  // byte offset in 8KB plane tile
                int row = o >> 6;              // 0..127
                int kb = o & 63;               // byte within 64B k-chunk
                int rg = min(baseRow + row, rClamp);
                uint4 v = *(const uint4*)((const char*)src + (size_t)rg * 512 + (size_t)k0 * 2 + kb);
                *(uint4*)((char*)&lds[p][row][0] + kb) = v;
            }
        };
        stage(Ahi, m0, M - 1, 0);
        stage(Alo, m0, M - 1, 1);
        stage(Bhi, n0, DO - 1, 2);
        stage(Blo, n0, DO - 1, 3);
        __syncthreads();

        bf16x8 bh[4], bl[4];
#pragma unroll
        for (int ni = 0; ni < 4; ni++) {
            bh[ni] = *(const bf16x8*)&lds[2][wn * 64 + ni * 16 + rsel][ksel];
            bl[ni] = *(const bf16x8*)&lds[3][wn * 64 + ni * 16 + rsel][ksel];
        }
#pragma unroll
        for (int mi = 0; mi < 4; mi++) {
            bf16x8 ah = *(const bf16x8*)&lds[0][wm * 64 + mi * 16 + rsel][ksel];
            bf16x8 al = *(const bf16x8*)&lds[1][wm * 64 + mi * 16 + rsel][ksel];
#pragma unroll
            for (int ni = 0; ni < 4; ni++) {
                acc[mi][ni] = __builtin_amdgcn_mfma_f32_16x16x32_bf16(ah, bh[ni], acc[mi][ni], 0, 0, 0);
                acc[mi][ni] = __builtin_amdgcn_mfma_f32_16x16x32_bf16(ah, bl[ni], acc[mi][ni], 0, 0, 0);
                acc[mi][ni] = __builtin_amdgcn_mfma_f32_16x16x32_bf16(al, bh[ni], acc[mi][ni], 0, 0, 0);
            }
        }
        __syncthreads();
    }

    // epilogue: C/D layout col=lane&15, row=(lane>>4)*4+j  [m89-verified]; fp16 store
#pragma unroll
    for (int mi = 0; mi < 4; mi++) {
#pragma unroll
        for (int j = 0; j < 4; j++) {
            int r = m0 + wm * 64 + mi * 16 + (lane >> 4) * 4 + j;
            if (r < M) {
                float dv = dinv[r];
#pragma unroll
                for (int ni = 0; ni < 4; ni++) {
                    int c = n0 + wn * 64 + ni * 16 + rsel;
                    C[(size_t)r * DO + c] = __float2half_rn(acc[mi][ni][j] * dv);
                }
            }
        }
    }
}

// ---------------- CSR aggregation over fp16 rows (8-deep gather pipeline) ----------------
// MODE 1: val = relu(val*pa+pc), write bf16 hi/lo planes. MODE 0: val = val + pa, write fp32.
template <int D, int MODE>
__global__ __launch_bounds__(256) void agg_kernel(const __half* __restrict__ Hs, const int* __restrict__ base,
                                                  const int* __restrict__ counts, const float* __restrict__ dinv,
                                                  const int* __restrict__ col,
                                                  const float* __restrict__ pa, const float* __restrict__ pc,
                                                  float* __restrict__ outF, ushort* __restrict__ outHi,
                                                  ushort* __restrict__ outLo, int M) {
    constexpr int V = D / 64;  // halfs per lane: 4 (D=256) or 2 (D=128)
    int w = blockIdx.x * 4 + (threadIdx.x >> 6);
    if (w >= M) return;
    int lane = threadIdx.x & 63;
    const char* gbase = (const char*)(Hs + lane * V);  // + s*D*2 bytes per row
    float acc[V];
#pragma unroll
    for (int j = 0; j < V; j++) acc[j] = 0.f;

    auto accum32 = [&](unsigned bits, int j2) {  // add 2 halfs packed in u32
        __half2 h = *(__half2*)&bits;
        float2 f = __half22float2(h);
        acc[j2 + 0] += f.x;
        acc[j2 + 1] += f.y;
    };

    // self loop
    if constexpr (V == 4) {
        uint2 r = *(const uint2*)(gbase + (size_t)w * D * 2);
        accum32(r.x, 0); accum32(r.y, 2);
    } else {
        unsigned r = *(const unsigned*)(gbase + (size_t)w * D * 2);
        accum32(r, 0);
    }

    int e = base[w], end = e + counts[w];
    // 8 rows in flight
    for (; e + 8 <= end; e += 8) {
        int idx[8];
#pragma unroll
        for (int t = 0; t < 8; t++) idx[t] = col[e + t];
        if constexpr (V == 4) {
            uint2 r[8];
#pragma unroll
            for (int t = 0; t < 8; t++) r[t] = *(const uint2*)(gbase + (size_t)idx[t] * (D * 2));
#pragma unroll
            for (int t = 0; t < 8; t++) { accum32(r[t].x, 0); accum32(r[t].y, 2); }
        } else {
            unsigned r[8];
#pragma unroll
            for (int t = 0; t < 8; t++) r[t] = *(const unsigned*)(gbase + (size_t)idx[t] * (D * 2));
#pragma unroll
            for (int t = 0; t < 8; t++) accum32(r[t], 0);
        }
    }
    for (; e < end; e++) {
        int s = col[e];
        if constexpr (V == 4) {
            uint2 r = *(const uint2*)(gbase + (size_t)s * (D * 2));
            accum32(r.x, 0); accum32(r.y, 2);
        } else {
            unsigned r = *(const unsigned*)(gbase + (size_t)s * (D * 2));
            accum32(r, 0);
        }
    }

    float dv = dinv[w];
    if constexpr (MODE == 1) {
        ushort4 h, l;
        float val;
        int d = lane * V;
        val = fmaxf(fmaf(acc[0] * dv, pa[d + 0], pc[d + 0]), 0.f);
        h.x = f2bf_rn(val); l.x = f2bf_rn(val - bf2f(h.x));
        val = fmaxf(fmaf(acc[1] * dv, pa[d + 1], pc[d + 1]), 0.f);
        h.y = f2bf_rn(val); l.y = f2bf_rn(val - bf2f(h.y));
        val = fmaxf(fmaf(acc[2] * dv, pa[d + 2], pc[d + 2]), 0.f);
        h.z = f2bf_rn(val); l.z = f2bf_rn(val - bf2f(h.z));
        val = fmaxf(fmaf(acc[3] * dv, pa[d + 3], pc[d + 3]), 0.f);
        h.w = f2bf_rn(val); l.w = f2bf_rn(val - bf2f(h.w));
        *(ushort4*)&outHi[(size_t)w * D + d] = h;
        *(ushort4*)&outLo[(size_t)w * D + d] = l;
    } else {
#pragma unroll
        for (int j = 0; j < V; j++) {
            int d = lane * V + j;
            outF[(size_t)w * D + d] = acc[j] * dv + pa[d];
        }
    }
}

// ---------------- launch ----------------

extern "C" void kernel_launch(void* const* d_in, const int* in_sizes, int n_in,
                              void* d_out, int out_size, void* d_ws, size_t ws_size,
                              hipStream_t stream) {
    const float* x = (const float*)d_in[0];
    const int* ei = (const int*)d_in[1];
    const int* srcIdx = ei;
    const int* dstIdx = ei + GE;
    const float* W1 = (const float*)d_in[2];
    const float* b1 = (const float*)d_in[3];
    const float* g1 = (const float*)d_in[4];
    const float* be1 = (const float*)d_in[5];
    const float* m1 = (const float*)d_in[6];
    const float* v1 = (const float*)d_in[7];
    const float* W2 = (const float*)d_in[8];
    const float* b2 = (const float*)d_in[9];
    const float* g2 = (const float*)d_in[10];
    const float* be2 = (const float*)d_in[11];
    const float* m2 = (const float*)d_in[12];
    const float* v2 = (const float*)d_in[13];
    const float* W3 = (const float*)d_in[14];
    const float* b3 = (const float*)d_in[15];
    float* out = (float*)d_out;

    size_t off = 0;
    char* wsb = (char*)d_ws;
    auto take = [&](size_t bytes) -> char* {
        char* p = wsb + off;
        off += (bytes + 255) & ~(size_t)255;
        return p;
    };
    float* dinv = (float*)take((size_t)GN * 4);
    int* counts = (int*)take((size_t)GN * 4);
    int* cursor = (int*)take((size_t)GN * 4);
    int* segbase = (int*)take((size_t)GN * 4);
    int* total = (int*)take(256);
    int* col = (int*)take((size_t)GE * 4);
    float* prm = (float*)take(4 * 256 * 4);
    __half* hH = (__half*)take((size_t)GN * 256 * 2);   // GEMM output (fp16), reused all layers
    ushort* Phi = (ushort*)take((size_t)GN * 256 * 2);  // activation hi plane (x-planes aliased here)
    ushort* Plo = (ushort*)take((size_t)GN * 256 * 2);  // activation lo plane
    ushort* WT1h = (ushort*)take(256 * 256 * 2);
    ushort* WT1l = (ushort*)take(256 * 256 * 2);
    ushort* WT2h = (ushort*)take(256 * 256 * 2);
    ushort* WT2l = (ushort*)take(256 * 256 * 2);
    ushort* WT3h = (ushort*)take(128 * 256 * 2);
    ushort* WT3l = (ushort*)take(128 * 256 * 2);

    const float* a1 = prm + 0 * 256;
    const float* c1 = prm + 1 * 256;
    const float* a2 = prm + 2 * 256;
    const float* c2 = prm + 3 * 256;

    int nb = (GN + 255) / 256;
    int eb = (GE + 255) / 256;

    init_kernel<<<nb, 256, 0, stream>>>(counts, cursor, total);
    count_kernel<<<eb, 256, 0, stream>>>(dstIdx, counts);
    dinv_kernel<<<nb, 256, 0, stream>>>(counts, dinv);
    alloc_kernel<<<nb, 256, 0, stream>>>(counts, segbase, total);
    fill_kernel<<<eb, 256, 0, stream>>>(srcIdx, dstIdx, segbase, cursor, col);
    params_kernel<<<1, 256, 0, stream>>>(b1, g1, be1, m1, v1, b2, g2, be2, m2, v2, prm);

    // pre-passes: split x and W transposes into bf16 hi/lo
    int n4 = GN * 64;  // GN*256/4 float4s
    conv_split<<<(n4 + 255) / 256, 256, 0, stream>>>(x, Phi, Plo, n4);
    transpose_w<<<(256 * 256 + 255) / 256, 256, 0, stream>>>(W1, WT1h, WT1l, 256);
    transpose_w<<<(256 * 256 + 255) / 256, 256, 0, stream>>>(W2, WT2h, WT2l, 256);
    transpose_w<<<(128 * 256 + 255) / 256, 256, 0, stream>>>(W3, WT3h, WT3l, 128);

    dim3 gg((GN + 127) / 128, 2);
    dim3 gg3((GN + 127) / 128, 1);
    int ab = (GN + 3) / 4;

    // layer 1
    gemm_mfma<256><<<gg, 256, 0, stream>>>(Phi, Plo, WT1h, WT1l, dinv, hH, GN);
    agg_kernel<256, 1><<<ab, 256, 0, stream>>>(hH, segbase, counts, dinv, col, a1, c1, nullptr, Phi, Plo, GN);
    // layer 2
    gemm_mfma<256><<<gg, 256, 0, stream>>>(Phi, Plo, WT2h, WT2l, dinv, hH, GN);
    agg_kernel<256, 1><<<ab, 256, 0, stream>>>(hH, segbase, counts, dinv, col, a2, c2, nullptr, Phi, Plo, GN);
    // layer 3
    gemm_mfma<128><<<gg3, 256, 0, stream>>>(Phi, Plo, WT3h, WT3l, dinv, hH, GN);
    agg_kernel<128, 0><<<ab, 256, 0, stream>>>(hH, segbase, counts, dinv, col, b3, b3, out, nullptr, nullptr, GN);
}

// Round 11
// 451.240 us; speedup vs baseline: 1.8415x; 1.0803x over previous
//
#include <hip/hip_runtime.h>
#include <hip/hip_bf16.h>
#include <hip/hip_fp16.h>

// GCN 3-layer forward.
// CSR build (count -> fused dinv+atomic segment alloc -> fill) -> per layer:
//   asymmetric fp16 MFMA GEMM (A: 1 fp16 plane; W: fp16 hi+lo planes; 2 MFMAs)
//   -> CSR agg over fp16 rows (8-deep gather pipeline, BN/ReLU, fp16 plane out).
// Numerics: C = a16*(bh+bl); error (a-a16)*b ~ 2^-11 rel (~5e-4/layer), under the
// fp16-hop floor (3.9e-3 measured). Round-10 counters: agg at path roofline
// (188MB = 8 XCD x fp16 matrix @ 3.8TB/s); GEMM was 3-term bf16 -> cut to 2-term fp16.

#define GN 50000
#define GE 800000

typedef float f32x4 __attribute__((ext_vector_type(4)));
typedef _Float16 f16x8 __attribute__((ext_vector_type(8)));

// ---------------- graph setup ----------------

__global__ __launch_bounds__(256) void init_kernel(int* counts, int* cursor, int* total) {
    int i = blockIdx.x * 256 + threadIdx.x;
    if (i < GN) { counts[i] = 0; cursor[i] = 0; }
    if (i == 0) *total = 0;
}

__global__ __launch_bounds__(256) void count_kernel(const int* __restrict__ dst, int* __restrict__ counts) {
    int e = blockIdx.x * 256 + threadIdx.x;
    if (e < GE) atomicAdd(&counts[dst[e]], 1);
}

// fused: dinv + disjoint CSR segment allocation (wave shfl-scan + 1 atomic/wave)
__global__ __launch_bounds__(256) void alloc_kernel(const int* __restrict__ counts, float* __restrict__ dinv,
                                                    int* __restrict__ base, int* __restrict__ total) {
    int i = blockIdx.x * 256 + threadIdx.x;
    int lane = threadIdx.x & 63;
    int c = (i < GN) ? counts[i] : 0;
    if (i < GN) dinv[i] = rsqrtf((float)c + 1.0f);
    int v = c;
#pragma unroll
    for (int off = 1; off < 64; off <<= 1) {
        int t = __shfl_up(v, off);
        if (lane >= off) v += t;
    }
    int waveSum = __shfl(v, 63);
    int wb = 0;
    if (lane == 63) wb = atomicAdd(total, waveSum);
    wb = __shfl(wb, 63);
    if (i < GN) base[i] = wb + v - c;  // exclusive intra-wave prefix + wave base
}

__global__ __launch_bounds__(256) void fill_kernel(const int* __restrict__ src, const int* __restrict__ dst,
                                                   const int* __restrict__ base, int* __restrict__ cursor,
                                                   int* __restrict__ col) {
    int e = blockIdx.x * 256 + threadIdx.x;
    if (e < GE) {
        int d = dst[e];
        int pos = base[d] + atomicAdd(&cursor[d], 1);
        col[pos] = src[e];
    }
}

__global__ __launch_bounds__(256) void params_kernel(
    const float* b1, const float* g1, const float* be1, const float* m1, const float* v1,
    const float* b2, const float* g2, const float* be2, const float* m2, const float* v2,
    float* prm) {
    int t = threadIdx.x;
    float s1 = g1[t] * rsqrtf(v1[t] + 1e-5f);
    prm[0 * 256 + t] = s1;
    prm[1 * 256 + t] = (b1[t] - m1[t]) * s1 + be1[t];
    float s2 = g2[t] * rsqrtf(v2[t] + 1e-5f);
    prm[2 * 256 + t] = s2;
    prm[3 * 256 + t] = (b2[t] - m2[t]) * s2 + be2[t];
}

// ---------------- pre-passes ----------------

// x fp32 -> single fp16 plane
__global__ __launch_bounds__(256) void conv_x(const float* __restrict__ in, ushort* __restrict__ out, int n4) {
    int i = blockIdx.x * 256 + threadIdx.x;
    if (i >= n4) return;
    float4 v = *(const float4*)&in[(size_t)i * 4];
    ushort4 h;
    h.x = __half_as_ushort(__float2half_rn(v.x));
    h.y = __half_as_ushort(__float2half_rn(v.y));
    h.z = __half_as_ushort(__float2half_rn(v.z));
    h.w = __half_as_ushort(__float2half_rn(v.w));
    *(ushort4*)&out[(size_t)i * 4] = h;
}

// all three W [256][DO] fp32 -> WT hi/lo fp16 [DO][256], one kernel
__global__ __launch_bounds__(256) void transpose_all(const float* __restrict__ W1, const float* __restrict__ W2,
                                                     const float* __restrict__ W3,
                                                     ushort* __restrict__ T1h, ushort* __restrict__ T1l,
                                                     ushort* __restrict__ T2h, ushort* __restrict__ T2l,
                                                     ushort* __restrict__ T3h, ushort* __restrict__ T3l) {
    int idx = blockIdx.x * 256 + threadIdx.x;
    const float* W;
    ushort *Th, *Tl;
    int i, DO;
    if (idx < 65536) { W = W1; Th = T1h; Tl = T1l; i = idx; DO = 256; }
    else if (idx < 131072) { W = W2; Th = T2h; Tl = T2l; i = idx - 65536; DO = 256; }
    else if (idx < 163840) { W = W3; Th = T3h; Tl = T3l; i = idx - 131072; DO = 128; }
    else return;
    int n = i >> 8, k = i & 255;
    float v = W[k * DO + n];
    __half h = __float2half_rn(v);
    Th[i] = __half_as_ushort(h);
    Tl[i] = __half_as_ushort(__float2half_rn(v - __half2float(h)));
}

// ---------------- asymmetric fp16 MFMA GEMM ----------------
// C[m][n] = dinv[m] * sum_k A[m][k]*W[k][n]; A: fp16 plane [M][256];
// W: transposed fp16 hi/lo planes [DO][256]. BM=128,BN=128,BK=32; 4 waves (2x2), 64x64/wave.

template <int DO>
__global__ __launch_bounds__(256) void gemm_mfma(const ushort* __restrict__ A16, const ushort* __restrict__ Bhi,
                                                 const ushort* __restrict__ Blo, const float* __restrict__ dinv,
                                                 __half* __restrict__ C, int M) {
    __shared__ ushort lds[3][128][40];  // 80B rows (pad 16B) -> <=2-way bank conflict on ds_read_b128
    int tid = threadIdx.x;
    int lane = tid & 63;
    int wave = tid >> 6;
    int wm = wave >> 1, wn = wave & 1;
    int m0 = blockIdx.x * 128;
    int n0 = blockIdx.y * 128;
    int rsel = lane & 15;
    int ksel = (lane >> 4) * 8;

    f32x4 acc[4][4] = {};

    for (int k0 = 0; k0 < 256; k0 += 32) {
        auto stage = [&](const ushort* __restrict__ src, int baseRow, int rClamp, int p) {
#pragma unroll
            for (int j = 0; j < 2; j++) {
                int o = (tid + j * 256) * 16;  // byte offset in 8KB plane tile
                int row = o >> 6;              // 0..127
                int kb = o & 63;               // byte within 64B k-chunk
                int rg = min(baseRow + row, rClamp);
                uint4 v = *(const uint4*)((const char*)src + (size_t)rg * 512 + (size_t)k0 * 2 + kb);
                *(uint4*)((char*)&lds[p][row][0] + kb) = v;
            }
        };
        stage(A16, m0, M - 1, 0);
        stage(Bhi, n0, DO - 1, 1);
        stage(Blo, n0, DO - 1, 2);
        __syncthreads();

        f16x8 bh[4], bl[4];
#pragma unroll
        for (int ni = 0; ni < 4; ni++) {
            bh[ni] = *(const f16x8*)&lds[1][wn * 64 + ni * 16 + rsel][ksel];
            bl[ni] = *(const f16x8*)&lds[2][wn * 64 + ni * 16 + rsel][ksel];
        }
#pragma unroll
        for (int mi = 0; mi < 4; mi++) {
            f16x8 av = *(const f16x8*)&lds[0][wm * 64 + mi * 16 + rsel][ksel];
#pragma unroll
            for (int ni = 0; ni < 4; ni++) {
                acc[mi][ni] = __builtin_amdgcn_mfma_f32_16x16x32_f16(av, bh[ni], acc[mi][ni], 0, 0, 0);
                acc[mi][ni] = __builtin_amdgcn_mfma_f32_16x16x32_f16(av, bl[ni], acc[mi][ni], 0, 0, 0);
            }
        }
        __syncthreads();
    }

    // epilogue: C/D layout col=lane&15, row=(lane>>4)*4+j  [m89-verified]; fp16 store
#pragma unroll
    for (int mi = 0; mi < 4; mi++) {
#pragma unroll
        for (int j = 0; j < 4; j++) {
            int r = m0 + wm * 64 + mi * 16 + (lane >> 4) * 4 + j;
            if (r < M) {
                float dv = dinv[r];
#pragma unroll
                for (int ni = 0; ni < 4; ni++) {
                    int c = n0 + wn * 64 + ni * 16 + rsel;
                    C[(size_t)r * DO + c] = __float2half_rn(acc[mi][ni][j] * dv);
                }
            }
        }
    }
}

// ---------------- CSR aggregation over fp16 rows (8-deep gather pipeline) ----------------
// MODE 1: val = relu(val*pa+pc), write fp16 plane. MODE 0: val = val + pa, write fp32.
template <int D, int MODE>
__global__ __launch_bounds__(256) void agg_kernel(const __half* __restrict__ Hs, const int* __restrict__ base,
                                                  const int* __restrict__ counts, const float* __restrict__ dinv,
                                                  const int* __restrict__ col,
                                                  const float* __restrict__ pa, const float* __restrict__ pc,
                                                  float* __restrict__ outF, ushort* __restrict__ outH, int M) {
    constexpr int V = D / 64;   // halfs per lane: 4 (D=256) or 2 (D=128)
    constexpr int P = V / 2;    // float2 accumulators
    int w = blockIdx.x * 4 + (threadIdx.x >> 6);
    if (w >= M) return;
    int lane = threadIdx.x & 63;
    const char* gbase = (const char*)(Hs + lane * V);  // + s*D*2 bytes per row
    float2 acc2[P];
#pragma unroll
    for (int j = 0; j < P; j++) acc2[j] = make_float2(0.f, 0.f);

    auto accum32 = [&](unsigned bits, int j2) {  // add 2 halfs packed in u32 (pk-add friendly)
        __half2 h = *(__half2*)&bits;
        float2 f = __half22float2(h);
        acc2[j2].x += f.x;
        acc2[j2].y += f.y;
    };

    // self loop
    if constexpr (V == 4) {
        uint2 r = *(const uint2*)(gbase + (size_t)w * D * 2);
        accum32(r.x, 0); accum32(r.y, 1);
    } else {
        unsigned r = *(const unsigned*)(gbase + (size_t)w * D * 2);
        accum32(r, 0);
    }

    int e = base[w], end = e + counts[w];
    // 8 rows in flight
    for (; e + 8 <= end; e += 8) {
        int idx[8];
#pragma unroll
        for (int t = 0; t < 8; t++) idx[t] = col[e + t];
        if constexpr (V == 4) {
            uint2 r[8];
#pragma unroll
            for (int t = 0; t < 8; t++) r[t] = *(const uint2*)(gbase + (size_t)idx[t] * (D * 2));
#pragma unroll
            for (int t = 0; t < 8; t++) { accum32(r[t].x, 0); accum32(r[t].y, 1); }
        } else {
            unsigned r[8];
#pragma unroll
            for (int t = 0; t < 8; t++) r[t] = *(const unsigned*)(gbase + (size_t)idx[t] * (D * 2));
#pragma unroll
            for (int t = 0; t < 8; t++) accum32(r[t], 0);
        }
    }
    for (; e < end; e++) {
        int s = col[e];
        if constexpr (V == 4) {
            uint2 r = *(const uint2*)(gbase + (size_t)s * (D * 2));
            accum32(r.x, 0); accum32(r.y, 1);
        } else {
            unsigned r = *(const unsigned*)(gbase + (size_t)s * (D * 2));
            accum32(r, 0);
        }
    }

    float dv = dinv[w];
    float acc[V];
#pragma unroll
    for (int j = 0; j < P; j++) { acc[2 * j] = acc2[j].x; acc[2 * j + 1] = acc2[j].y; }

    if constexpr (MODE == 1) {
        ushort4 h;
        int d = lane * V;
        float val;
        val = fmaxf(fmaf(acc[0] * dv, pa[d + 0], pc[d + 0]), 0.f);
        h.x = __half_as_ushort(__float2half_rn(val));
        val = fmaxf(fmaf(acc[1] * dv, pa[d + 1], pc[d + 1]), 0.f);
        h.y = __half_as_ushort(__float2half_rn(val));
        val = fmaxf(fmaf(acc[2] * dv, pa[d + 2], pc[d + 2]), 0.f);
        h.z = __half_as_ushort(__float2half_rn(val));
        val = fmaxf(fmaf(acc[3] * dv, pa[d + 3], pc[d + 3]), 0.f);
        h.w = __half_as_ushort(__float2half_rn(val));
        *(ushort4*)&outH[(size_t)w * D + d] = h;
    } else {
#pragma unroll
        for (int j = 0; j < V; j++) {
            int d = lane * V + j;
            outF[(size_t)w * D + d] = acc[j] * dv + pa[d];
        }
    }
}

// ---------------- launch ----------------

extern "C" void kernel_launch(void* const* d_in, const int* in_sizes, int n_in,
                              void* d_out, int out_size, void* d_ws, size_t ws_size,
                              hipStream_t stream) {
    const float* x = (const float*)d_in[0];
    const int* ei = (const int*)d_in[1];
    const int* srcIdx = ei;
    const int* dstIdx = ei + GE;
    const float* W1 = (const float*)d_in[2];
    const float* b1 = (const float*)d_in[3];
    const float* g1 = (const float*)d_in[4];
    const float* be1 = (const float*)d_in[5];
    const float* m1 = (const float*)d_in[6];
    const float* v1 = (const float*)d_in[7];
    const float* W2 = (const float*)d_in[8];
    const float* b2 = (const float*)d_in[9];
    const float* g2 = (const float*)d_in[10];
    const float* be2 = (const float*)d_in[11];
    const float* m2 = (const float*)d_in[12];
    const float* v2 = (const float*)d_in[13];
    const float* W3 = (const float*)d_in[14];
    const float* b3 = (const float*)d_in[15];
    float* out = (float*)d_out;

    size_t off = 0;
    char* wsb = (char*)d_ws;
    auto take = [&](size_t bytes) -> char* {
        char* p = wsb + off;
        off += (bytes + 255) & ~(size_t)255;
        return p;
    };
    float* dinv = (float*)take((size_t)GN * 4);
    int* counts = (int*)take((size_t)GN * 4);
    int* cursor = (int*)take((size_t)GN * 4);
    int* segbase = (int*)take((size_t)GN * 4);
    int* total = (int*)take(256);
    int* col = (int*)take((size_t)GE * 4);
    float* prm = (float*)take(4 * 256 * 4);
    __half* hH = (__half*)take((size_t)GN * 256 * 2);  // GEMM output (fp16)
    ushort* P = (ushort*)take((size_t)GN * 256 * 2);   // activation fp16 plane (x16 aliased)
    ushort* X16 = P;                                   // layer-1 A: fp16(x); consumed before agg writes P
    ushort* WT1h = (ushort*)take(256 * 256 * 2);
    ushort* WT1l = (ushort*)take(256 * 256 * 2);
    ushort* WT2h = (ushort*)take(256 * 256 * 2);
    ushort* WT2l = (ushort*)take(256 * 256 * 2);
    ushort* WT3h = (ushort*)take(128 * 256 * 2);
    ushort* WT3l = (ushort*)take(128 * 256 * 2);

    const float* a1 = prm + 0 * 256;
    const float* c1 = prm + 1 * 256;
    const float* a2 = prm + 2 * 256;
    const float* c2 = prm + 3 * 256;

    int nb = (GN + 255) / 256;
    int eb = (GE + 255) / 256;

    init_kernel<<<nb, 256, 0, stream>>>(counts, cursor, total);
    count_kernel<<<eb, 256, 0, stream>>>(dstIdx, counts);
    alloc_kernel<<<nb, 256, 0, stream>>>(counts, dinv, segbase, total);
    fill_kernel<<<eb, 256, 0, stream>>>(srcIdx, dstIdx, segbase, cursor, col);
    params_kernel<<<1, 256, 0, stream>>>(b1, g1, be1, m1, v1, b2, g2, be2, m2, v2, prm);

    int n4 = GN * 64;  // GN*256/4 float4s
    conv_x<<<(n4 + 255) / 256, 256, 0, stream>>>(x, X16, n4);
    transpose_all<<<(163840 + 255) / 256, 256, 0, stream>>>(W1, W2, W3, WT1h, WT1l, WT2h, WT2l, WT3h, WT3l);

    dim3 gg((GN + 127) / 128, 2);
    dim3 gg3((GN + 127) / 128, 1);
    int ab = (GN + 3) / 4;

    // layer 1
    gemm_mfma<256><<<gg, 256, 0, stream>>>(X16, WT1h, WT1l, dinv, hH, GN);
    agg_kernel<256, 1><<<ab, 256, 0, stream>>>(hH, segbase, counts, dinv, col, a1, c1, nullptr, P, GN);
    // layer 2
    gemm_mfma<256><<<gg, 256, 0, stream>>>(P, WT2h, WT2l, dinv, hH, GN);
    agg_kernel<256, 1><<<ab, 256, 0, stream>>>(hH, segbase, counts, dinv, col, a2, c2, nullptr, P, GN);
    // layer 3
    gemm_mfma<128><<<gg3, 256, 0, stream>>>(P, WT3h, WT3l, dinv, hH, GN);
    agg_kernel<128, 0><<<ab, 256, 0, stream>>>(hH, segbase, counts, dinv, col, b3, b3, out, nullptr, GN);
}